// Round 8
// baseline (205.040 us; speedup 1.0000x reference)
//
#include <hip/hip_runtime.h>
#include <hip/hip_bf16.h>

// Problem constants
#define BB   2
#define TT   2048
#define DD   1024
#define HH   16
#define EE   64
#define BT   4096   // BB*TT

typedef __attribute__((ext_vector_type(8))) short bf16x8;    // 8 bf16 = 4 VGPRs
typedef __attribute__((ext_vector_type(4))) float floatx4;   // 16x16 mfma C/D
typedef __attribute__((ext_vector_type(16))) float floatx16; // 32x32 mfma C/D

__device__ __forceinline__ unsigned short f2bf(float f) {
  unsigned int x = __float_as_uint(f);
  x += 0x7fffu + ((x >> 16) & 1u);   // round-to-nearest-even
  return (unsigned short)(x >> 16);
}
__device__ __forceinline__ unsigned int pack2u(float a, float b) {
  union { __hip_bfloat162 h; unsigned int u; } r;
  r.h = __float22bfloat162_rn(make_float2(a, b));
  return r.u;
}
// 8x fp32 -> 8x bf16 (RNE) packed; uses v_cvt_pk_bf16_f32 on gfx950
__device__ __forceinline__ uint4 pack8(const float4& a, const float4& b) {
  union { uint4 u; __hip_bfloat162 h[4]; } r;
  r.h[0] = __float22bfloat162_rn(make_float2(a.x, a.y));
  r.h[1] = __float22bfloat162_rn(make_float2(a.z, a.w));
  r.h[2] = __float22bfloat162_rn(make_float2(b.x, b.y));
  r.h[3] = __float22bfloat162_rn(make_float2(b.z, b.w));
  return r.u;
}
// async global->LDS, 16 B per lane; LDS dest = wave-uniform base + lane*16
__device__ __forceinline__ void ld16(unsigned short* lds, const unsigned short* g) {
  __builtin_amdgcn_global_load_lds(
      (const __attribute__((address_space(1))) unsigned int*)g,
      (__attribute__((address_space(3))) unsigned int*)lds, 16, 0, 0);
}

// ---------------------------------------------------------------------------
// Pre-pass: fp32 -> bf16 for X, [Wq;Wkv], Wout. One group = 8 elems.
// ---------------------------------------------------------------------------
#define GX   524288
#define GWQ  131072
#define GWKV 262144
#define GWO  131072

__global__ __launch_bounds__(256) void convert_kernel(
    const float* __restrict__ X,  const float* __restrict__ Wq,
    const float* __restrict__ Wkv, const float* __restrict__ Wout,
    unsigned short* __restrict__ Xb, unsigned short* __restrict__ Wb,
    unsigned short* __restrict__ Wob) {
  int g = blockIdx.x * 256 + threadIdx.x;
  const float* src; unsigned short* dst; int gi;
  if (g < GX)                        { src = X;    dst = Xb;  gi = g; }
  else if ((g -= GX) < GWQ)          { src = Wq;   dst = Wb;  gi = g; }
  else if ((g -= GWQ) < GWKV)        { src = Wkv;  dst = Wb + (size_t)GWQ * 8; gi = g; }
  else                               { src = Wout; dst = Wob; gi = g - GWKV; }
  const float4* s4 = reinterpret_cast<const float4*>(src) + (size_t)gi * 2;
  float4 a = s4[0], b = s4[1];
  reinterpret_cast<uint4*>(dst)[gi] = pack8(a, b);
}

// ---------------------------------------------------------------------------
// MFMA GEMM 1 (m97-style): C = Xb[4096,1024] @ Wb[3072,1024]^T, all bf16.
// Epilogue: head-split; Q (PRE-SCALED by 0.125) / K -> [bh][t][e], V -> [bh][e][t].
// ---------------------------------------------------------------------------
__global__ __launch_bounds__(256) void gemm_qkv_mfma(
    const unsigned short* __restrict__ Xb,
    const unsigned short* __restrict__ Wb,
    unsigned short* __restrict__ Qh,
    unsigned short* __restrict__ Kh,
    unsigned short* __restrict__ Vt) {
  __shared__ __align__(16) unsigned short As[128 * 64];
  __shared__ __align__(16) unsigned short Bs[128 * 64];
  const int tid  = threadIdx.x;
  const int lane = tid & 63, w = tid >> 6;
  const int wm = w >> 1, wn = w & 1;
  const int q = lane >> 4, c = lane & 15;
  const int bm0 = blockIdx.y * 128;
  const int bn0 = blockIdx.x * 128;
  const unsigned short* Ag = Xb + (size_t)bm0 * DD;
  const unsigned short* Bg = Wb + (size_t)bn0 * DD;

  floatx4 acc[4][4];
#pragma unroll
  for (int i = 0; i < 4; ++i)
#pragma unroll
    for (int j = 0; j < 4; ++j) acc[i][j] = (floatx4){0.f, 0.f, 0.f, 0.f};

  int prow[4], pch[4];
#pragma unroll
  for (int t = 0; t < 4; ++t) {
    int s = (w * 4 + t) * 64 + lane;
    prow[t] = s >> 3;
    pch[t]  = (s & 7) ^ (prow[t] & 7);
  }
  int aoff[4][2], boff[4][2];
#pragma unroll
  for (int i = 0; i < 4; ++i)
#pragma unroll
    for (int h = 0; h < 2; ++h) {
      aoff[i][h] = (wm * 64 + i * 16 + c) * 64 + (((q + h * 4) ^ (c & 7)) << 3);
      boff[i][h] = (wn * 64 + i * 16 + c) * 64 + (((q + h * 4) ^ (c & 7)) << 3);
    }

  for (int kk = 0; kk < DD; kk += 64) {
    __syncthreads();
#pragma unroll
    for (int t = 0; t < 4; ++t) {
      int i = w * 4 + t;
      ld16(&As[i * 512], &Ag[(size_t)prow[t] * DD + kk + pch[t] * 8]);
      ld16(&Bs[i * 512], &Bg[(size_t)prow[t] * DD + kk + pch[t] * 8]);
    }
    __syncthreads();
    bf16x8 af[4][2], bfr[4][2];
#pragma unroll
    for (int i = 0; i < 4; ++i)
#pragma unroll
      for (int h = 0; h < 2; ++h) {
        af[i][h]  = *reinterpret_cast<const bf16x8*>(&As[aoff[i][h]]);
        bfr[i][h] = *reinterpret_cast<const bf16x8*>(&Bs[boff[i][h]]);
      }
#pragma unroll
    for (int i = 0; i < 4; ++i)
#pragma unroll
      for (int j = 0; j < 4; ++j) {
        acc[i][j] = __builtin_amdgcn_mfma_f32_16x16x32_bf16(af[i][0], bfr[j][0], acc[i][j], 0, 0, 0);
        acc[i][j] = __builtin_amdgcn_mfma_f32_16x16x32_bf16(af[i][1], bfr[j][1], acc[i][j], 0, 0, 0);
      }
  }

  const int region = bn0 >> 10;   // 0=Q, 1=K, 2=V
  const float scl = (region == 0) ? 0.125f : 1.0f;   // fold e^-0.5 into Q
#pragma unroll
  for (int i = 0; i < 4; ++i) {
#pragma unroll
    for (int j = 0; j < 4; ++j) {
#pragma unroll
      for (int reg = 0; reg < 4; ++reg) {
        int m = bm0 + wm * 64 + i * 16 + q * 4 + reg;
        int n = bn0 + wn * 64 + j * 16 + c;
        int nb = n & 1023;
        int h = nb >> 6, e = nb & 63;
        int b = m >> 11, t = m & 2047;
        unsigned short v = f2bf(acc[i][j][reg] * scl);
        if (region == 0)      Qh[((size_t)((b * HH + h) * TT + t)) * EE + e] = v;
        else if (region == 1) Kh[((size_t)((b * HH + h) * TT + t)) * EE + e] = v;
        else                  Vt[((size_t)(b * HH + h)) * EE * TT + (size_t)e * TT + t] = v;
      }
    }
  }
}

// ---------------------------------------------------------------------------
// MFMA flash attention v3: 128-thread blocks (2 waves), wave owns 64 q-rows
// (2 sets of 32). Q + O + P all in registers. K/V double-buffered in LDS via
// global_load_lds; raw s_barrier + manual vmcnt(8) (no full drain).
// S^T = K.Q^T; PV uses a PERMUTED k-order so the lane's own exp'd C-layout
// quads serve directly as the A-frag; V supplies the matching order via two
// ds_read_b64 per frag (chunk-halves at byte offset 8g).
// 32x32 layouts (HW-verified rounds 4-7): A/B: m|n=lane&31, k=(lane>>5)*8+j;
// C/D: col=lane&31, row=(reg&3)+8*(reg>>2)+4*(lane>>5).
// ---------------------------------------------------------------------------
__global__ __launch_bounds__(128) void attn_kernel(
    const unsigned short* __restrict__ Qh,
    const unsigned short* __restrict__ Kh,
    const unsigned short* __restrict__ Vtg,
    unsigned short* __restrict__ Aw) {
  __shared__ __align__(16) unsigned short Ks[2][64 * 64];  // [t][e], swizzled
  __shared__ __align__(16) unsigned short Vs[2][64 * 64];  // [e][t], swizzled

  const int tid  = threadIdx.x;
  const int lane = tid & 63;
  const int w    = tid >> 6;      // wave 0..1 -> q-rows [w*64, w*64+64)
  const int n31  = lane & 31;
  const int g    = lane >> 5;

  const int qt = blockIdx.x;      // 0..15 (128 q-rows per block)
  const int bh = blockIdx.y;      // 0..31
  const size_t base = (size_t)bh * TT * EE;
  const unsigned short* Qp = Qh + base + (size_t)(qt * 128 + w * 64) * EE;
  const unsigned short* Kp = Kh + base;
  const unsigned short* Vp = Vtg + base;

  // Q B-frags in registers: [set][kc]; row set*32+n31, e-chunk kc*16+g*8
  bf16x8 qf[2][4];
#pragma unroll
  for (int s = 0; s < 2; ++s)
#pragma unroll
    for (int kc = 0; kc < 4; ++kc)
      qf[s][kc] = *reinterpret_cast<const bf16x8*>(
          &Qp[(size_t)(s * 32 + n31) * EE + kc * 16 + g * 8]);

  // staging slots: 4 calls/thread per matrix (8 KB tile, 128 threads)
  int srow[4], sch[4];
#pragma unroll
  for (int t = 0; t < 4; ++t) {
    int s = (t * 2 + w) * 64 + lane;
    srow[t] = s >> 3;
    sch[t]  = (s & 7) ^ (srow[t] & 7);
  }

  floatx16 o_acc[2][2];           // [set][eh]
  o_acc[0][0] = (floatx16)(0.0f); o_acc[0][1] = (floatx16)(0.0f);
  o_acc[1][0] = (floatx16)(0.0f); o_acc[1][1] = (floatx16)(0.0f);
  float l_sum[2] = {0.0f, 0.0f};

  // prime tile 0 into buf 0
#pragma unroll
  for (int t = 0; t < 4; ++t) {
    ld16(&Ks[0][(t * 2 + w) * 512], &Kp[(size_t)srow[t] * EE + sch[t] * 8]);
    ld16(&Vs[0][(t * 2 + w) * 512], &Vp[(size_t)srow[t] * TT + sch[t] * 8]);
  }

  for (int kt = 0; kt < 32; ++kt) {
    const int p  = kt & 1;
    const int nk = (kt + 1) & 31;   // wraparound prefetch on last iter: harmless
    // stage next tile into the other buffer (its readers finished at the
    // end-of-iter barrier of kt-1)
#pragma unroll
    for (int t = 0; t < 4; ++t) {
      ld16(&Ks[p ^ 1][(t * 2 + w) * 512], &Kp[(size_t)(nk * 64 + srow[t]) * EE + sch[t] * 8]);
      ld16(&Vs[p ^ 1][(t * 2 + w) * 512], &Vp[(size_t)srow[t] * TT + nk * 64 + sch[t] * 8]);
    }
    // wait own 8 oldest DMAs (current tile) -> then barrier makes them
    // visible to the sibling wave; next tile's 8 stay in flight.
    asm volatile("s_waitcnt vmcnt(8)" ::: "memory");
    asm volatile("s_barrier" ::: "memory");

    const unsigned short* Kb = Ks[p];
    const unsigned short* Vb = Vs[p];

#pragma unroll
    for (int s = 0; s < 2; ++s) {
      // ---- S^T = K Q^T for q-set s: two 32x32 tiles (nt = kcol half) ----
      floatx16 sacc[2];
      sacc[0] = (floatx16)(0.0f);
      sacc[1] = (floatx16)(0.0f);
#pragma unroll
      for (int nt = 0; nt < 2; ++nt) {
        const int krow = nt * 32 + n31;
#pragma unroll
        for (int kc = 0; kc < 4; ++kc) {
          const int swch = (kc * 2 + g) ^ (krow & 7);
          bf16x8 kf = *reinterpret_cast<const bf16x8*>(&Kb[krow * 64 + swch * 8]);
          sacc[nt] = __builtin_amdgcn_mfma_f32_32x32x16_bf16(kf, qf[s][kc], sacc[nt], 0, 0, 0);
        }
      }
      // ---- p = exp(s); l += p; pack to bf16 pairs (all in registers) ----
      // lane holds qrow = s*32+n31; kcols (reg&3)+8*(reg>>2)+4g (+32nt)
      unsigned int pp[2][8] __attribute__((aligned(16)));
#pragma unroll
      for (int nt = 0; nt < 2; ++nt)
#pragma unroll
        for (int r = 0; r < 8; ++r) {
          float e0 = __expf(sacc[nt][2 * r]);
          float e1 = __expf(sacc[nt][2 * r + 1]);
          l_sum[s] += e0 + e1;
          pp[nt][r] = pack2u(e0, e1);
        }
      // ---- O += P V, permuted k-order ----
      // mfma (nt,kcp): lane g's k-slots j0..7 map to kcols
      //   nt*32 + kcp*16 + 4g + [0,4)  and  nt*32 + kcp*16 + 8 + 4g + [0,4)
      // = the lane's own quads 2kcp, 2kcp+1 -> pp[nt][4kcp .. 4kcp+3].
      // V must supply the same order: chunks (nt*4+2kcp), (nt*4+2kcp+1),
      // half-chunk at byte offset 8g.
#pragma unroll
      for (int nt = 0; nt < 2; ++nt)
#pragma unroll
        for (int kcp = 0; kcp < 2; ++kcp) {
          union { unsigned int u[4]; bf16x8 v; } pf;
          pf.u[0] = pp[nt][4 * kcp + 0]; pf.u[1] = pp[nt][4 * kcp + 1];
          pf.u[2] = pp[nt][4 * kcp + 2]; pf.u[3] = pp[nt][4 * kcp + 3];
#pragma unroll
          for (int eh = 0; eh < 2; ++eh) {
            const int vrow = eh * 32 + n31;
            const int c0 = (nt * 4 + 2 * kcp)     ^ (vrow & 7);
            const int c1 = (nt * 4 + 2 * kcp + 1) ^ (vrow & 7);
            uint2 v0 = *reinterpret_cast<const uint2*>(&Vb[vrow * 64 + c0 * 8 + g * 4]);
            uint2 v1 = *reinterpret_cast<const uint2*>(&Vb[vrow * 64 + c1 * 8 + g * 4]);
            union { unsigned int u[4]; bf16x8 v; } vf;
            vf.u[0] = v0.x; vf.u[1] = v0.y; vf.u[2] = v1.x; vf.u[3] = v1.y;
            o_acc[s][eh] = __builtin_amdgcn_mfma_f32_32x32x16_bf16(pf.v, vf.v, o_acc[s][eh], 0, 0, 0);
          }
        }
    }
    // all waves done reading buf p before iter kt+1 overwrites it
    asm volatile("s_barrier" ::: "memory");
  }

  // l: lanes n31 / n31+32 hold partials of q-row set*32+n31
  l_sum[0] += __shfl_xor(l_sum[0], 32, 64);
  l_sum[1] += __shfl_xor(l_sum[1], 32, 64);

  const int b = bh >> 4, h = bh & 15;
#pragma unroll
  for (int s = 0; s < 2; ++s) {
    float linv[16];
#pragma unroll
    for (int reg = 0; reg < 16; ++reg) {
      int qrl = (reg & 3) + 8 * (reg >> 2) + 4 * g;
      linv[reg] = 1.0f / __shfl(l_sum[s], qrl, 64);
    }
#pragma unroll
    for (int eh = 0; eh < 2; ++eh) {
      int e = eh * 32 + n31;
#pragma unroll
      for (int reg = 0; reg < 16; ++reg) {
        int qrl = (reg & 3) + 8 * (reg >> 2) + 4 * g;
        int t = qt * 128 + w * 64 + s * 32 + qrl;
        Aw[((size_t)(b * TT + t)) * DD + h * EE + e] = f2bf(o_acc[s][eh][reg] * linv[reg]);
      }
    }
  }
}

// ---------------------------------------------------------------------------
// MFMA GEMM 2: out = Aw[4096,1024](bf16) @ Wob[1024,1024]^T (bf16) + bias.
// Tile 128x64x64 (grid 512 = 2 blocks/CU).
// ---------------------------------------------------------------------------
__global__ __launch_bounds__(256) void gemm_out_mfma(
    const unsigned short* __restrict__ A,
    const unsigned short* __restrict__ Wob,
    const float* __restrict__ bias,
    float* __restrict__ out) {
  __shared__ __align__(16) unsigned short As[128 * 64];
  __shared__ __align__(16) unsigned short Bs[64 * 64];
  const int tid  = threadIdx.x;
  const int lane = tid & 63, w = tid >> 6;
  const int wm = w >> 1, wn = w & 1;
  const int q = lane >> 4, c = lane & 15;
  const int bm0 = blockIdx.y * 128;
  const int bn0 = blockIdx.x * 64;
  const unsigned short* Ag = A + (size_t)bm0 * DD;
  const unsigned short* Bg = Wob + (size_t)bn0 * DD;

  floatx4 acc[4][2];
#pragma unroll
  for (int i = 0; i < 4; ++i)
#pragma unroll
    for (int j = 0; j < 2; ++j) acc[i][j] = (floatx4){0.f, 0.f, 0.f, 0.f};

  int parow[4], pach[4];
#pragma unroll
  for (int t = 0; t < 4; ++t) {
    int s = (w * 4 + t) * 64 + lane;
    parow[t] = s >> 3;
    pach[t]  = (s & 7) ^ (parow[t] & 7);
  }
  int pbrow[2], pbch[2];
#pragma unroll
  for (int t = 0; t < 2; ++t) {
    int s = (w * 2 + t) * 64 + lane;
    pbrow[t] = s >> 3;
    pbch[t]  = (s & 7) ^ (pbrow[t] & 7);
  }

  for (int kk = 0; kk < DD; kk += 64) {
    __syncthreads();
#pragma unroll
    for (int t = 0; t < 4; ++t)
      ld16(&As[(w * 4 + t) * 512], &Ag[(size_t)parow[t] * DD + kk + pach[t] * 8]);
#pragma unroll
    for (int t = 0; t < 2; ++t)
      ld16(&Bs[(w * 2 + t) * 512], &Bg[(size_t)pbrow[t] * DD + kk + pbch[t] * 8]);
    __syncthreads();
    bf16x8 af[4][2], bfr[2][2];
#pragma unroll
    for (int h = 0; h < 2; ++h) {
      int ksw = ((q + h * 4) ^ (c & 7)) << 3;
#pragma unroll
      for (int i = 0; i < 4; ++i)
        af[i][h] = *reinterpret_cast<const bf16x8*>(&As[(wm * 64 + i * 16 + c) * 64 + ksw]);
#pragma unroll
      for (int j = 0; j < 2; ++j)
        bfr[j][h] = *reinterpret_cast<const bf16x8*>(&Bs[(wn * 32 + j * 16 + c) * 64 + ksw]);
    }
#pragma unroll
    for (int i = 0; i < 4; ++i)
#pragma unroll
      for (int j = 0; j < 2; ++j) {
        acc[i][j] = __builtin_amdgcn_mfma_f32_16x16x32_bf16(af[i][0], bfr[j][0], acc[i][j], 0, 0, 0);
        acc[i][j] = __builtin_amdgcn_mfma_f32_16x16x32_bf16(af[i][1], bfr[j][1], acc[i][j], 0, 0, 0);
      }
  }

#pragma unroll
  for (int i = 0; i < 4; ++i) {
#pragma unroll
    for (int j = 0; j < 2; ++j) {
      int n = bn0 + wn * 32 + j * 16 + c;
      float bv = bias[n];
#pragma unroll
      for (int reg = 0; reg < 4; ++reg) {
        int m = bm0 + wm * 64 + i * 16 + q * 4 + reg;
        out[(size_t)m * DD + n] = acc[i][j][reg] + bv;
      }
    }
  }
}

// ---------------------------------------------------------------------------
extern "C" void kernel_launch(void* const* d_in, const int* in_sizes, int n_in,
                              void* d_out, int out_size, void* d_ws, size_t ws_size,
                              hipStream_t stream) {
  const float* X    = (const float*)d_in[0];
  const float* Wq   = (const float*)d_in[1];
  const float* Wkv  = (const float*)d_in[2];
  const float* Wout = (const float*)d_in[3];
  const float* bout = (const float*)d_in[4];
  float* out = (float*)d_out;

  unsigned short* Qh  = (unsigned short*)d_ws;            // [32][2048][64]
  unsigned short* Kh  = Qh + (size_t)BT * DD;             // [32][2048][64]
  unsigned short* Vt  = Kh + (size_t)BT * DD;             // [32][64][2048]
  unsigned short* Aw  = Vt + (size_t)BT * DD;             // [4096][1024]
  unsigned short* Xb  = Aw;                               // OVERLAY: dead before attn writes Aw
  unsigned short* Wb  = Aw + (size_t)BT * DD;             // [3072][1024]
  unsigned short* Wob = Wb + (size_t)3 * 1024 * DD;       // [1024][1024]

  convert_kernel<<<dim3(4096), 256, 0, stream>>>(X, Wq, Wkv, Wout, Xb, Wb, Wob);
  gemm_qkv_mfma<<<dim3(24, 32), 256, 0, stream>>>(Xb, Wb, Qh, Kh, Vt);
  attn_kernel<<<dim3(16, 32), 128, 0, stream>>>(Qh, Kh, Vt, Aw);
  gemm_out_mfma<<<dim3(16, 32), 256, 0, stream>>>(Aw, Wob, bout, out);
}

// Round 9
// 200.721 us; speedup vs baseline: 1.0215x; 1.0215x over previous
//
#include <hip/hip_runtime.h>
#include <hip/hip_bf16.h>

// Problem constants
#define BB   2
#define TT   2048
#define DD   1024
#define HH   16
#define EE   64
#define BT   4096   // BB*TT

typedef __attribute__((ext_vector_type(8))) short bf16x8;    // 8 bf16 = 4 VGPRs
typedef __attribute__((ext_vector_type(4))) float floatx4;   // 16x16 mfma C/D
typedef __attribute__((ext_vector_type(16))) float floatx16; // 32x32 mfma C/D

__device__ __forceinline__ unsigned short f2bf(float f) {
  unsigned int x = __float_as_uint(f);
  x += 0x7fffu + ((x >> 16) & 1u);   // round-to-nearest-even
  return (unsigned short)(x >> 16);
}
__device__ __forceinline__ unsigned int pack2u(float a, float b) {
  union { __hip_bfloat162 h; unsigned int u; } r;
  r.h = __float22bfloat162_rn(make_float2(a, b));
  return r.u;
}
// 8x fp32 -> 8x bf16 (RNE) packed; uses v_cvt_pk_bf16_f32 on gfx950
__device__ __forceinline__ uint4 pack8(const float4& a, const float4& b) {
  union { uint4 u; __hip_bfloat162 h[4]; } r;
  r.h[0] = __float22bfloat162_rn(make_float2(a.x, a.y));
  r.h[1] = __float22bfloat162_rn(make_float2(a.z, a.w));
  r.h[2] = __float22bfloat162_rn(make_float2(b.x, b.y));
  r.h[3] = __float22bfloat162_rn(make_float2(b.z, b.w));
  return r.u;
}
// async global->LDS, 16 B per lane; LDS dest = wave-uniform base + lane*16
__device__ __forceinline__ void ld16(unsigned short* lds, const unsigned short* g) {
  __builtin_amdgcn_global_load_lds(
      (const __attribute__((address_space(1))) unsigned int*)g,
      (__attribute__((address_space(3))) unsigned int*)lds, 16, 0, 0);
}

// ---------------------------------------------------------------------------
// Pre-pass: fp32 -> bf16 for X, [Wq;Wkv], Wout. One group = 8 elems.
// ---------------------------------------------------------------------------
#define GX   524288
#define GWQ  131072
#define GWKV 262144
#define GWO  131072

__global__ __launch_bounds__(256) void convert_kernel(
    const float* __restrict__ X,  const float* __restrict__ Wq,
    const float* __restrict__ Wkv, const float* __restrict__ Wout,
    unsigned short* __restrict__ Xb, unsigned short* __restrict__ Wb,
    unsigned short* __restrict__ Wob) {
  int g = blockIdx.x * 256 + threadIdx.x;
  const float* src; unsigned short* dst; int gi;
  if (g < GX)                        { src = X;    dst = Xb;  gi = g; }
  else if ((g -= GX) < GWQ)          { src = Wq;   dst = Wb;  gi = g; }
  else if ((g -= GWQ) < GWKV)        { src = Wkv;  dst = Wb + (size_t)GWQ * 8; gi = g; }
  else                               { src = Wout; dst = Wob; gi = g - GWKV; }
  const float4* s4 = reinterpret_cast<const float4*>(src) + (size_t)gi * 2;
  float4 a = s4[0], b = s4[1];
  reinterpret_cast<uint4*>(dst)[gi] = pack8(a, b);
}

// ---------------------------------------------------------------------------
// MFMA GEMM 1 (m97-style): C = Xb[4096,1024] @ Wb[3072,1024]^T, all bf16.
// Epilogue: head-split; Q PRE-SCALED by 0.125*log2(e) (softmax uses exp2);
// Q/K -> [bh][t][e], V -> [bh][e][t].
// ---------------------------------------------------------------------------
__global__ __launch_bounds__(256) void gemm_qkv_mfma(
    const unsigned short* __restrict__ Xb,
    const unsigned short* __restrict__ Wb,
    unsigned short* __restrict__ Qh,
    unsigned short* __restrict__ Kh,
    unsigned short* __restrict__ Vt) {
  __shared__ __align__(16) unsigned short As[128 * 64];
  __shared__ __align__(16) unsigned short Bs[128 * 64];
  const int tid  = threadIdx.x;
  const int lane = tid & 63, w = tid >> 6;
  const int wm = w >> 1, wn = w & 1;
  const int q = lane >> 4, c = lane & 15;
  const int bm0 = blockIdx.y * 128;
  const int bn0 = blockIdx.x * 128;
  const unsigned short* Ag = Xb + (size_t)bm0 * DD;
  const unsigned short* Bg = Wb + (size_t)bn0 * DD;

  floatx4 acc[4][4];
#pragma unroll
  for (int i = 0; i < 4; ++i)
#pragma unroll
    for (int j = 0; j < 4; ++j) acc[i][j] = (floatx4){0.f, 0.f, 0.f, 0.f};

  int prow[4], pch[4];
#pragma unroll
  for (int t = 0; t < 4; ++t) {
    int s = (w * 4 + t) * 64 + lane;
    prow[t] = s >> 3;
    pch[t]  = (s & 7) ^ (prow[t] & 7);
  }
  int aoff[4][2], boff[4][2];
#pragma unroll
  for (int i = 0; i < 4; ++i)
#pragma unroll
    for (int h = 0; h < 2; ++h) {
      aoff[i][h] = (wm * 64 + i * 16 + c) * 64 + (((q + h * 4) ^ (c & 7)) << 3);
      boff[i][h] = (wn * 64 + i * 16 + c) * 64 + (((q + h * 4) ^ (c & 7)) << 3);
    }

  for (int kk = 0; kk < DD; kk += 64) {
    __syncthreads();
#pragma unroll
    for (int t = 0; t < 4; ++t) {
      int i = w * 4 + t;
      ld16(&As[i * 512], &Ag[(size_t)prow[t] * DD + kk + pch[t] * 8]);
      ld16(&Bs[i * 512], &Bg[(size_t)prow[t] * DD + kk + pch[t] * 8]);
    }
    __syncthreads();
    bf16x8 af[4][2], bfr[4][2];
#pragma unroll
    for (int i = 0; i < 4; ++i)
#pragma unroll
      for (int h = 0; h < 2; ++h) {
        af[i][h]  = *reinterpret_cast<const bf16x8*>(&As[aoff[i][h]]);
        bfr[i][h] = *reinterpret_cast<const bf16x8*>(&Bs[boff[i][h]]);
      }
#pragma unroll
    for (int i = 0; i < 4; ++i)
#pragma unroll
      for (int j = 0; j < 4; ++j) {
        acc[i][j] = __builtin_amdgcn_mfma_f32_16x16x32_bf16(af[i][0], bfr[j][0], acc[i][j], 0, 0, 0);
        acc[i][j] = __builtin_amdgcn_mfma_f32_16x16x32_bf16(af[i][1], bfr[j][1], acc[i][j], 0, 0, 0);
      }
  }

  const int region = bn0 >> 10;   // 0=Q, 1=K, 2=V
  // Q scale: e^-0.5 * log2(e) so attention can use raw exp2
  const float scl = (region == 0) ? 0.18033688011112042f : 1.0f;
#pragma unroll
  for (int i = 0; i < 4; ++i) {
#pragma unroll
    for (int j = 0; j < 4; ++j) {
#pragma unroll
      for (int reg = 0; reg < 4; ++reg) {
        int m = bm0 + wm * 64 + i * 16 + q * 4 + reg;
        int n = bn0 + wn * 64 + j * 16 + c;
        int nb = n & 1023;
        int h = nb >> 6, e = nb & 63;
        int b = m >> 11, t = m & 2047;
        unsigned short v = f2bf(acc[i][j][reg] * scl);
        if (region == 0)      Qh[((size_t)((b * HH + h) * TT + t)) * EE + e] = v;
        else if (region == 1) Kh[((size_t)((b * HH + h) * TT + t)) * EE + e] = v;
        else                  Vt[((size_t)(b * HH + h)) * EE * TT + (size_t)e * TT + t] = v;
      }
    }
  }
}

// ---------------------------------------------------------------------------
// MFMA flash attention v4: 256-thread blocks = 2 q-row-halves x 2 K-chunks.
// Wave (wv, p2) owns q-rows [wv*64, wv*64+64) for K-tiles [p2*16, p2*16+16).
// Fixed-offset softmax => partials combine by plain addition (no rescale):
// chunk-1 waves dump O(fp32)+l into dead K/V LDS; chunk-0 waves add/divide.
// Per-wave structure = round 8 (HW-verified): Q/O/P in registers, K/V dbuf
// via global_load_lds + s_barrier + vmcnt(8), permuted-k PV, exp2 softmax.
// 32x32 layouts: A/B: m|n=lane&31, k=(lane>>5)*8+j;
//                C/D: col=lane&31, row=(reg&3)+8*(reg>>2)+4*(lane>>5).
// ---------------------------------------------------------------------------
#define CHUNK 16

__global__ __launch_bounds__(256) void attn_kernel(
    const unsigned short* __restrict__ Qh,
    const unsigned short* __restrict__ Kh,
    const unsigned short* __restrict__ Vtg,
    unsigned short* __restrict__ Aw) {
  __shared__ __align__(16) unsigned short smem[32768];   // 64 KB

  const int tid  = threadIdx.x;
  const int lane = tid & 63;
  const int w    = tid >> 6;
  const int wv   = w & 1;         // q-row half
  const int p2   = w >> 1;        // k-chunk
  const int n31  = lane & 31;
  const int g    = lane >> 5;

  const int qt = blockIdx.x;      // 0..15
  const int bh = blockIdx.y;      // 0..31
  const size_t base = (size_t)bh * TT * EE;
  const unsigned short* Qp = Qh + base + (size_t)(qt * 128 + wv * 64) * EE;
  const unsigned short* Kp = Kh + base;
  const unsigned short* Vp = Vtg + base;

  // per-pair K/V double buffers (pair = waves sharing chunk p2, both wv)
  unsigned short* Kbuf = smem + p2 * 16384;          // [buf][4096]
  unsigned short* Vbuf = smem + p2 * 16384 + 8192;   // [buf][4096]

  // Q B-frags in registers: [set][kc]; row set*32+n31, e-chunk kc*16+g*8
  bf16x8 qf[2][4];
#pragma unroll
  for (int s = 0; s < 2; ++s)
#pragma unroll
    for (int kc = 0; kc < 4; ++kc)
      qf[s][kc] = *reinterpret_cast<const bf16x8*>(
          &Qp[(size_t)(s * 32 + n31) * EE + kc * 16 + g * 8]);

  // staging slots: pair = 128 threads; 8 KB tile = 512 slots -> 4/thread
  int srow[4], sch[4];
#pragma unroll
  for (int t = 0; t < 4; ++t) {
    int s = (t * 2 + wv) * 64 + lane;
    srow[t] = s >> 3;
    sch[t]  = (s & 7) ^ (srow[t] & 7);
  }

  floatx16 o_acc[2][2];           // [set][eh]
  o_acc[0][0] = (floatx16)(0.0f); o_acc[0][1] = (floatx16)(0.0f);
  o_acc[1][0] = (floatx16)(0.0f); o_acc[1][1] = (floatx16)(0.0f);
  float l_sum[2] = {0.0f, 0.0f};

  const int kt0 = p2 * CHUNK;
  // prime tile kt0 into buf 0
#pragma unroll
  for (int t = 0; t < 4; ++t) {
    ld16(&Kbuf[(t * 2 + wv) * 512], &Kp[(size_t)(kt0 * 64 + srow[t]) * EE + sch[t] * 8]);
    ld16(&Vbuf[(t * 2 + wv) * 512], &Vp[(size_t)srow[t] * TT + kt0 * 64 + sch[t] * 8]);
  }

  for (int kt = 0; kt < CHUNK; ++kt) {
    const int p  = kt & 1;
    const int gt = kt0 + ((kt + 1) & (CHUNK - 1));   // wraparound prefetch: harmless
#pragma unroll
    for (int t = 0; t < 4; ++t) {
      ld16(&Kbuf[(p ^ 1) * 4096 + (t * 2 + wv) * 512],
           &Kp[(size_t)(gt * 64 + srow[t]) * EE + sch[t] * 8]);
      ld16(&Vbuf[(p ^ 1) * 4096 + (t * 2 + wv) * 512],
           &Vp[(size_t)srow[t] * TT + gt * 64 + sch[t] * 8]);
    }
    // wait own 8 oldest DMAs (current tile); next tile's 8 stay in flight
    asm volatile("s_waitcnt vmcnt(8)" ::: "memory");
    asm volatile("s_barrier" ::: "memory");

    const unsigned short* Kb = Kbuf + p * 4096;
    const unsigned short* Vb = Vbuf + p * 4096;

    // hoist K fragments (s-invariant): 8 x ds_read_b128
    bf16x8 kf[2][4];
#pragma unroll
    for (int nt = 0; nt < 2; ++nt) {
      const int krow = nt * 32 + n31;
#pragma unroll
      for (int kc = 0; kc < 4; ++kc) {
        const int swch = (kc * 2 + g) ^ (krow & 7);
        kf[nt][kc] = *reinterpret_cast<const bf16x8*>(&Kb[krow * 64 + swch * 8]);
      }
    }

#pragma unroll
    for (int s = 0; s < 2; ++s) {
      // ---- S^T = K Q^T ----
      floatx16 sacc[2];
      sacc[0] = (floatx16)(0.0f);
      sacc[1] = (floatx16)(0.0f);
#pragma unroll
      for (int nt = 0; nt < 2; ++nt)
#pragma unroll
        for (int kc = 0; kc < 4; ++kc)
          sacc[nt] = __builtin_amdgcn_mfma_f32_32x32x16_bf16(kf[nt][kc], qf[s][kc], sacc[nt], 0, 0, 0);

      // ---- p = exp2(s) (log2e folded into Q); l += p; pack bf16 pairs ----
      unsigned int pp[2][8] __attribute__((aligned(16)));
#pragma unroll
      for (int nt = 0; nt < 2; ++nt)
#pragma unroll
        for (int r = 0; r < 8; ++r) {
          float e0 = __builtin_amdgcn_exp2f(sacc[nt][2 * r]);
          float e1 = __builtin_amdgcn_exp2f(sacc[nt][2 * r + 1]);
          l_sum[s] += e0 + e1;
          pp[nt][r] = pack2u(e0, e1);
        }

      // ---- O += P V, permuted k-order (P stays in registers) ----
#pragma unroll
      for (int nt = 0; nt < 2; ++nt)
#pragma unroll
        for (int kcp = 0; kcp < 2; ++kcp) {
          union { unsigned int u[4]; bf16x8 v; } pf;
          pf.u[0] = pp[nt][4 * kcp + 0]; pf.u[1] = pp[nt][4 * kcp + 1];
          pf.u[2] = pp[nt][4 * kcp + 2]; pf.u[3] = pp[nt][4 * kcp + 3];
#pragma unroll
          for (int eh = 0; eh < 2; ++eh) {
            const int vrow = eh * 32 + n31;
            const int c0 = (nt * 4 + 2 * kcp)     ^ (vrow & 7);
            const int c1 = (nt * 4 + 2 * kcp + 1) ^ (vrow & 7);
            uint2 v0 = *reinterpret_cast<const uint2*>(&Vb[vrow * 64 + c0 * 8 + g * 4]);
            uint2 v1 = *reinterpret_cast<const uint2*>(&Vb[vrow * 64 + c1 * 8 + g * 4]);
            union { unsigned int u[4]; bf16x8 v; } vf;
            vf.u[0] = v0.x; vf.u[1] = v0.y; vf.u[2] = v1.x; vf.u[3] = v1.y;
            o_acc[s][eh] = __builtin_amdgcn_mfma_f32_32x32x16_bf16(pf.v, vf.v, o_acc[s][eh], 0, 0, 0);
          }
        }
    }
    asm volatile("s_barrier" ::: "memory");
  }

  // per-row l totals (lanes n31 / n31+32 hold the two kcol-halves)
  l_sum[0] += __shfl_xor(l_sum[0], 32, 64);
  l_sum[1] += __shfl_xor(l_sum[1], 32, 64);

  // ---- split-K combine through LDS (K/V buffers are dead now) ----
  __syncthreads();   // full drain incl. wraparound DMAs, then repurpose smem
  float* fb = (float*)smem;   // Obuf: [wv][64 rows][66] ; Lbuf at 8448 + wv*64
  if (p2 == 1) {
#pragma unroll
    for (int s = 0; s < 2; ++s) {
#pragma unroll
      for (int eh = 0; eh < 2; ++eh)
#pragma unroll
        for (int reg = 0; reg < 16; ++reg) {
          int qrl = (reg & 3) + 8 * (reg >> 2) + 4 * g;
          fb[wv * 4224 + (s * 32 + qrl) * 66 + eh * 32 + n31] = o_acc[s][eh][reg];
        }
      if (g == 0) fb[8448 + wv * 64 + s * 32 + n31] = l_sum[s];
    }
  }
  __syncthreads();
  if (p2 == 0) {
    const int b = bh >> 4, h = bh & 15;
#pragma unroll
    for (int s = 0; s < 2; ++s) {
      float linv[16];
#pragma unroll
      for (int reg = 0; reg < 16; ++reg) {
        int qrl = (reg & 3) + 8 * (reg >> 2) + 4 * g;
        float lown = __shfl(l_sum[s], qrl, 64);          // own chunk, row total
        float lpar = fb[8448 + wv * 64 + s * 32 + qrl];  // partner chunk (broadcast)
        linv[reg] = 1.0f / (lown + lpar);
      }
#pragma unroll
      for (int eh = 0; eh < 2; ++eh)
#pragma unroll
        for (int reg = 0; reg < 16; ++reg) {
          int qrl = (reg & 3) + 8 * (reg >> 2) + 4 * g;
          float o = o_acc[s][eh][reg] + fb[wv * 4224 + (s * 32 + qrl) * 66 + eh * 32 + n31];
          int t = qt * 128 + wv * 64 + s * 32 + qrl;
          Aw[((size_t)(b * TT + t)) * DD + h * EE + eh * 32 + n31] = f2bf(o * linv[reg]);
        }
    }
  }
}

// ---------------------------------------------------------------------------
// MFMA GEMM 2: out = Aw[4096,1024](bf16) @ Wob[1024,1024]^T (bf16) + bias.
// Tile 128x64x64 (grid 512 = 2 blocks/CU).
// ---------------------------------------------------------------------------
__global__ __launch_bounds__(256) void gemm_out_mfma(
    const unsigned short* __restrict__ A,
    const unsigned short* __restrict__ Wob,
    const float* __restrict__ bias,
    float* __restrict__ out) {
  __shared__ __align__(16) unsigned short As[128 * 64];
  __shared__ __align__(16) unsigned short Bs[64 * 64];
  const int tid  = threadIdx.x;
  const int lane = tid & 63, w = tid >> 6;
  const int wm = w >> 1, wn = w & 1;
  const int q = lane >> 4, c = lane & 15;
  const int bm0 = blockIdx.y * 128;
  const int bn0 = blockIdx.x * 64;
  const unsigned short* Ag = A + (size_t)bm0 * DD;
  const unsigned short* Bg = Wob + (size_t)bn0 * DD;

  floatx4 acc[4][2];
#pragma unroll
  for (int i = 0; i < 4; ++i)
#pragma unroll
    for (int j = 0; j < 2; ++j) acc[i][j] = (floatx4){0.f, 0.f, 0.f, 0.f};

  int parow[4], pach[4];
#pragma unroll
  for (int t = 0; t < 4; ++t) {
    int s = (w * 4 + t) * 64 + lane;
    parow[t] = s >> 3;
    pach[t]  = (s & 7) ^ (parow[t] & 7);
  }
  int pbrow[2], pbch[2];
#pragma unroll
  for (int t = 0; t < 2; ++t) {
    int s = (w * 2 + t) * 64 + lane;
    pbrow[t] = s >> 3;
    pbch[t]  = (s & 7) ^ (pbrow[t] & 7);
  }

  for (int kk = 0; kk < DD; kk += 64) {
    __syncthreads();
#pragma unroll
    for (int t = 0; t < 4; ++t)
      ld16(&As[(w * 4 + t) * 512], &Ag[(size_t)parow[t] * DD + kk + pach[t] * 8]);
#pragma unroll
    for (int t = 0; t < 2; ++t)
      ld16(&Bs[(w * 2 + t) * 512], &Bg[(size_t)pbrow[t] * DD + kk + pbch[t] * 8]);
    __syncthreads();
    bf16x8 af[4][2], bfr[2][2];
#pragma unroll
    for (int h = 0; h < 2; ++h) {
      int ksw = ((q + h * 4) ^ (c & 7)) << 3;
#pragma unroll
      for (int i = 0; i < 4; ++i)
        af[i][h] = *reinterpret_cast<const bf16x8*>(&As[(wm * 64 + i * 16 + c) * 64 + ksw]);
#pragma unroll
      for (int j = 0; j < 2; ++j)
        bfr[j][h] = *reinterpret_cast<const bf16x8*>(&Bs[(wn * 32 + j * 16 + c) * 64 + ksw]);
    }
#pragma unroll
    for (int i = 0; i < 4; ++i)
#pragma unroll
      for (int j = 0; j < 2; ++j) {
        acc[i][j] = __builtin_amdgcn_mfma_f32_16x16x32_bf16(af[i][0], bfr[j][0], acc[i][j], 0, 0, 0);
        acc[i][j] = __builtin_amdgcn_mfma_f32_16x16x32_bf16(af[i][1], bfr[j][1], acc[i][j], 0, 0, 0);
      }
  }

#pragma unroll
  for (int i = 0; i < 4; ++i) {
#pragma unroll
    for (int j = 0; j < 2; ++j) {
      int n = bn0 + wn * 32 + j * 16 + c;
      float bv = bias[n];
#pragma unroll
      for (int reg = 0; reg < 4; ++reg) {
        int m = bm0 + wm * 64 + i * 16 + q * 4 + reg;
        out[(size_t)m * DD + n] = acc[i][j][reg] + bv;
      }
    }
  }
}

// ---------------------------------------------------------------------------
extern "C" void kernel_launch(void* const* d_in, const int* in_sizes, int n_in,
                              void* d_out, int out_size, void* d_ws, size_t ws_size,
                              hipStream_t stream) {
  const float* X    = (const float*)d_in[0];
  const float* Wq   = (const float*)d_in[1];
  const float* Wkv  = (const float*)d_in[2];
  const float* Wout = (const float*)d_in[3];
  const float* bout = (const float*)d_in[4];
  float* out = (float*)d_out;

  unsigned short* Qh  = (unsigned short*)d_ws;            // [32][2048][64]
  unsigned short* Kh  = Qh + (size_t)BT * DD;             // [32][2048][64]
  unsigned short* Vt  = Kh + (size_t)BT * DD;             // [32][64][2048]
  unsigned short* Aw  = Vt + (size_t)BT * DD;             // [4096][1024]
  unsigned short* Xb  = Aw;                               // OVERLAY: dead before attn writes Aw
  unsigned short* Wb  = Aw + (size_t)BT * DD;             // [3072][1024]
  unsigned short* Wob = Wb + (size_t)3 * 1024 * DD;       // [1024][1024]

  convert_kernel<<<dim3(4096), 256, 0, stream>>>(X, Wq, Wkv, Wout, Xb, Wb, Wob);
  gemm_qkv_mfma<<<dim3(24, 32), 256, 0, stream>>>(Xb, Wb, Qh, Kh, Vt);
  attn_kernel<<<dim3(16, 32), 256, 0, stream>>>(Qh, Kh, Vt, Aw);
  gemm_out_mfma<<<dim3(16, 32), 256, 0, stream>>>(Aw, Wob, bout, out);
}